// Round 3
// baseline (88.804 us; speedup 1.0000x reference)
//
#include <hip/hip_runtime.h>
#include <math.h>

typedef _Float16 half_t;
typedef _Float16 h2 __attribute__((ext_vector_type(2)));
typedef unsigned int uint;

#define TPB 256

__device__ __forceinline__ uint pack_h2f(float a, float b) {
  half_t ha = (half_t)a, hb = (half_t)b;
  unsigned short ua = __builtin_bit_cast(unsigned short, ha);
  unsigned short ub = __builtin_bit_cast(unsigned short, hb);
  return (uint)ua | ((uint)ub << 16);
}

__device__ __forceinline__ float fdot2f(uint f, uint w, float acc) {
#if __has_builtin(__builtin_amdgcn_fdot2)
  return __builtin_amdgcn_fdot2(__builtin_bit_cast(h2, f),
                                __builtin_bit_cast(h2, w), acc, false);
#else
  h2 a = __builtin_bit_cast(h2, f), b = __builtin_bit_cast(h2, w);
  acc = fmaf((float)a.x, (float)b.x, acc);
  return fmaf((float)a.y, (float)b.y, acc);
#endif
}

// 8-wide fp16 dot (basis · spline_w), fp32 accumulate
__device__ __forceinline__ float dot8b(uint2 fa, uint2 fb, uint4 w, float acc) {
  acc = fdot2f(fa.x, w.x, acc);
  acc = fdot2f(fa.y, w.y, acc);
  acc = fdot2f(fb.x, w.z, acc);
  acc = fdot2f(fb.y, w.w, acc);
  return acc;
}

// Uniform-knot cubic B-spline + silu features -> 6-dword LDS slot.
// halves 0..7: dense 8-basis fp16 (only 4 nonzero, scattered);
// dword4: (silu_fp16, 0) -- OOR scatter targets land in half 9, which is
// always multiplied by a 0 weight half. dword5: alignment pad (never read).
__device__ __forceinline__ void feat_store(float x, uint* __restrict__ slot) {
  float e = __expf(-x);
  float silu = x * __builtin_amdgcn_rcpf(1.0f + e);
  float s = fmaf(x, 2.5f, 5.5f);          // (x - (-2.2)) / 0.4
  float sf = floorf(s);
  float t = s - sf;
  int p = (int)sf - 3;                    // first nonzero basis index
  float omt = 1.0f - t, t2 = t * t;
  float B[4];
  B[0] = (1.0f / 6.0f) * omt * omt * omt;
  B[3] = (1.0f / 6.0f) * t2 * t;
  B[1] = fmaf(0.5f * t, t2, 2.0f / 3.0f - t2);
  B[2] = 1.0f - B[0] - B[1] - B[3];       // partition of unity
  *(uint2*)slot = make_uint2(0u, 0u);
  *(uint2*)(slot + 2) = make_uint2(0u, 0u);
  slot[4] = (uint)__builtin_bit_cast(unsigned short, (half_t)silu);
  half_t* hp = (half_t*)slot;
#pragma unroll
  for (int k = 0; k < 4; ++k) {
    int g = p + k;
    int tgt = ((uint)g < 8u) ? g : 9;     // out-of-window -> dead half
    hp[tgt] = (half_t)B[k];
  }
}

// Packed weight buffer layout (dwords), built once in d_ws:
//  [0,72)    L1 spline:  [tap*8 + o*4 + j]   4x h2 (sw*scaler)
//  [72,90)   L1 base:    [tap*2 + o]         h2 (bw, 0)
//  [96,240)  L2 spline:  [wid*36 + tap*4 + j]  (wid = o*2+ci)
//  [240,276) L2 base:    [wid*9 + tap]       h2 (bw, 0)
__global__ void pack_w(const float* __restrict__ bw1, const float* __restrict__ sw1,
                       const float* __restrict__ sc1, const float* __restrict__ bw2,
                       const float* __restrict__ sw2, const float* __restrict__ sc2,
                       uint* __restrict__ W) {
  const int t = threadIdx.x;
  if (t < 18) {
    const int o = t / 9, tap = t - o * 9;
    const float scv = sc1[t];
#pragma unroll
    for (int j = 0; j < 4; ++j)
      W[tap * 8 + o * 4 + j] =
          pack_h2f(sw1[t * 8 + 2 * j] * scv, sw1[t * 8 + 2 * j + 1] * scv);
    W[72 + tap * 2 + o] = pack_h2f(bw1[t], 0.0f);
  } else if (t < 54) {
    const int q = t - 18;                  // q = wid*9 + tap
    const int wid = q / 9, tap = q - wid * 9;
    const float scv = sc2[q];
#pragma unroll
    for (int j = 0; j < 4; ++j)
      W[96 + wid * 36 + tap * 4 + j] =
          pack_h2f(sw2[q * 8 + 2 * j] * scv, sw2[q * 8 + 2 * j + 1] * scv);
    W[240 + wid * 9 + tap] = pack_h2f(bw2[q], 0.0f);
  }
}

// Column-parity remaps: consecutive lanes (pw stride 1, image-col stride 2)
// touch consecutive slots -> LDS lane stride 6 dwords (near-conflict-free).
#define REMAP30(col) (((col) >> 1) + ((col) & 1) * 15)
#define REMAP14(col) (((col) >> 1) + ((col) & 1) * 7)

__global__ __launch_bounds__(TPB, 5) void kan_fwd(
    const float* __restrict__ x, const uint* __restrict__ Wg,
    float* __restrict__ out)
{
  __shared__ __align__(16) uint lds[5400 + 2352 + 276];  // 32.1 KB -> 5 blk/CU
  uint* F1 = lds;              // 900 slots (30x30 padded), 6 dw each
  uint* F2 = lds + 5400;       // 2 x 196 slots (14x14)
  uint* WL = lds + 7752;       // packed weights (276 dw)
  float* P = (float*)lds;      // stage>=3 partials: 4*49*4 f32 (F1 dead)

  const int tid = threadIdx.x;
  const float* xb = x + (size_t)blockIdx.x * 784;

  // ---- Stage 0/1: weights -> LDS; features of padded 30x30 input ----
  for (int i = tid; i < 276; i += TPB) WL[i] = Wg[i];
  for (int s1 = tid; s1 < 900; s1 += TPB) {
    int row = s1 / 30, m = s1 - row * 30;
    int col = (m < 15) ? (2 * m) : (2 * (m - 15) + 1);   // undo parity remap
    bool inter = ((uint)(row - 1) < 28u) && ((uint)(col - 1) < 28u);
    int xi = min(max((row - 1) * 28 + (col - 1), 0), 783);
    float xv = xb[xi];
    xv = inter ? xv : 0.0f;
    feat_store(xv, F1 + s1 * 6);
  }
  __syncthreads();

  const int wv = tid >> 6;          // wave id 0..3
  const int lane = tid & 63;

  // ---- Stage 2: layer-1 conv (both o) + pool + layer-2 features ----
  if (lane < 49) {
    const int quad = wv * 49 + lane;          // 0..195
    const int ph = quad / 14, pw = quad - (quad / 14) * 14;
    const uint* base = F1 + ((2 * ph) * 30 + pw) * 6;
    float acc[2][4];
#pragma unroll
    for (int o = 0; o < 2; ++o)
#pragma unroll
      for (int q = 0; q < 4; ++q) acc[o][q] = 0.0f;

    // base pass: silu * bw, pixel-streaming, 18 weight dwords in VGPRs
    uint2 wb[9];
#pragma unroll
    for (int tp = 0; tp < 9; ++tp) wb[tp] = *(const uint2*)&WL[72 + tp * 2];
#pragma unroll
    for (int r = 0; r < 4; ++r) {
#pragma unroll
      for (int c = 0; c < 4; ++c) {
        uint sil = base[(r * 30 + REMAP30(c)) * 6 + 4];
#pragma unroll
        for (int dh = 0; dh < 2; ++dh) {
          if (r - dh < 0 || r - dh > 2) continue;
#pragma unroll
          for (int dw = 0; dw < 2; ++dw) {
            if (c - dw < 0 || c - dw > 2) continue;
            const int tap = (r - dh) * 3 + (c - dw);
            acc[0][dh * 2 + dw] = fdot2f(sil, wb[tap].x, acc[0][dh * 2 + dw]);
            acc[1][dh * 2 + dw] = fdot2f(sil, wb[tap].y, acc[1][dh * 2 + dw]);
          }
        }
      }
    }

    // spline pass: cache the 16 basis fragments, then tap-outer (no guards)
    uint2 basA[16], basB[16];
#pragma unroll
    for (int r = 0; r < 4; ++r) {
#pragma unroll
      for (int c = 0; c < 4; ++c) {
        const uint* sl = base + (r * 30 + REMAP30(c)) * 6;
        basA[r * 4 + c] = *(const uint2*)sl;
        basB[r * 4 + c] = *(const uint2*)(sl + 2);
      }
    }
#pragma unroll
    for (int tr = 0; tr < 3; ++tr) {
#pragma unroll
      for (int tc = 0; tc < 3; ++tc) {
        const int tap = tr * 3 + tc;
        uint4 w0 = *(const uint4*)&WL[tap * 8];
        uint4 w1 = *(const uint4*)&WL[tap * 8 + 4];
#pragma unroll
        for (int dh = 0; dh < 2; ++dh) {
#pragma unroll
          for (int dw = 0; dw < 2; ++dw) {
            const int px = (tr + dh) * 4 + (tc + dw);
            acc[0][dh * 2 + dw] = dot8b(basA[px], basB[px], w0, acc[0][dh * 2 + dw]);
            acc[1][dh * 2 + dw] = dot8b(basA[px], basB[px], w1, acc[1][dh * 2 + dw]);
          }
        }
      }
    }
#pragma unroll
    for (int o = 0; o < 2; ++o) {
      float mx = fmaxf(fmaxf(acc[o][0], acc[o][1]), fmaxf(acc[o][2], acc[o][3]));
      feat_store(mx, F2 + (o * 196 + ph * 14 + REMAP14(pw)) * 6);
    }
  }
  __syncthreads();

  // ---- Stage 3: layer-2 conv; wave wv = (o*2+ci), lane = 7x7 pool pos ----
  if (lane < 49) {
    const int wid = __builtin_amdgcn_readfirstlane(wv);
    const int ci = wid & 1;
    const int ph = lane / 7, pw = lane - (lane / 7) * 7;
    float pa[4] = {0.0f, 0.0f, 0.0f, 0.0f};

    // base pass
    uint wb2[9];
#pragma unroll
    for (int tp = 0; tp < 9; ++tp) wb2[tp] = WL[240 + wid * 9 + tp];
#pragma unroll
    for (int r = 0; r < 4; ++r) {
#pragma unroll
      for (int c = 0; c < 4; ++c) {
        int row = 2 * ph + r - 1, col = 2 * pw + c - 1;
        bool ok = ((uint)row < 14u) && ((uint)col < 14u);
        int rcl = min(max(row, 0), 13), ccl = min(max(col, 0), 13);
        uint sil = F2[(ci * 196 + rcl * 14 + REMAP14(ccl)) * 6 + 4];
        sil = ok ? sil : 0u;            // silu(0) = 0
#pragma unroll
        for (int dh = 0; dh < 2; ++dh) {
          if (r - dh < 0 || r - dh > 2) continue;
#pragma unroll
          for (int dw = 0; dw < 2; ++dw) {
            if (c - dw < 0 || c - dw > 2) continue;
            const int tap = (r - dh) * 3 + (c - dw);
            pa[dh * 2 + dw] = fdot2f(sil, wb2[tap], pa[dh * 2 + dw]);
          }
        }
      }
    }

    // spline pass: cache 16 fragments (OOB -> basis of x=0), tap-outer
    // basis(0): halves g2..g5 = 1/48, 23/48, 23/48, 1/48
    const uint F0d1 = pack_h2f(1.0f / 48.0f, 23.0f / 48.0f);
    const uint F0d2 = pack_h2f(23.0f / 48.0f, 1.0f / 48.0f);
    uint2 basA[16], basB[16];
#pragma unroll
    for (int r = 0; r < 4; ++r) {
#pragma unroll
      for (int c = 0; c < 4; ++c) {
        int row = 2 * ph + r - 1, col = 2 * pw + c - 1;
        bool ok = ((uint)row < 14u) && ((uint)col < 14u);
        int rcl = min(max(row, 0), 13), ccl = min(max(col, 0), 13);
        const uint* sl = F2 + (ci * 196 + rcl * 14 + REMAP14(ccl)) * 6;
        uint2 a = *(const uint2*)sl;
        uint2 b = *(const uint2*)(sl + 2);
        basA[r * 4 + c] = make_uint2(ok ? a.x : 0u, ok ? a.y : F0d1);
        basB[r * 4 + c] = make_uint2(ok ? b.x : F0d2, ok ? b.y : 0u);
      }
    }
#pragma unroll
    for (int tr = 0; tr < 3; ++tr) {
#pragma unroll
      for (int tc = 0; tc < 3; ++tc) {
        const int tap = tr * 3 + tc;
        uint4 w = *(const uint4*)&WL[96 + wid * 36 + tap * 4];
#pragma unroll
        for (int dh = 0; dh < 2; ++dh) {
#pragma unroll
          for (int dw = 0; dw < 2; ++dw) {
            const int px = (tr + dh) * 4 + (tc + dw);
            pa[dh * 2 + dw] = dot8b(basA[px], basB[px], w, pa[dh * 2 + dw]);
          }
        }
      }
    }
    *(float4*)&P[(wid * 49 + lane) * 4] = make_float4(pa[0], pa[1], pa[2], pa[3]);
  }
  __syncthreads();

  // ---- Stage 4: sum over ci, 2x2 maxpool, write (2,7,7) flat ----
  if (tid < 98) {
    const int o = tid / 49, pos = tid - o * 49;
    const float4 p0 = *(const float4*)&P[((o * 2 + 0) * 49 + pos) * 4];
    const float4 p1 = *(const float4*)&P[((o * 2 + 1) * 49 + pos) * 4];
    float m = fmaxf(fmaxf(p0.x + p1.x, p0.y + p1.y),
                    fmaxf(p0.z + p1.z, p0.w + p1.w));
    out[(size_t)blockIdx.x * 98 + tid] = m;
  }
}

extern "C" void kernel_launch(void* const* d_in, const int* in_sizes, int n_in,
                              void* d_out, int out_size, void* d_ws, size_t ws_size,
                              hipStream_t stream) {
  const float* x   = (const float*)d_in[0];
  const float* bw1 = (const float*)d_in[1];
  const float* sw1 = (const float*)d_in[2];
  const float* sc1 = (const float*)d_in[3];
  const float* bw2 = (const float*)d_in[4];
  const float* sw2 = (const float*)d_in[5];
  const float* sc2 = (const float*)d_in[6];
  float* out = (float*)d_out;
  uint* W = (uint*)d_ws;  // 276 dwords
  const int B = in_sizes[0] / 784;  // 2048
  pack_w<<<1, 64, 0, stream>>>(bw1, sw1, sc1, bw2, sw2, sc2, W);
  kan_fwd<<<B, TPB, 0, stream>>>(x, W, out);
}